// Round 8
// baseline (201.395 us; speedup 1.0000x reference)
//
#include <hip/hip_runtime.h>

#define B_SZ   8
#define SEQ    2048
#define PSEQ   (SEQ+16)     // 16 zero pad rows before each batch
#define SDIM   1024
#define DIN    512
#define DOUT   512
#define KX     10
#define RTOT   (B_SZ*SEQ)   // 16384
#define LC     64
#define NC     (SEQ/LC)     // 32

typedef __attribute__((ext_vector_type(8))) short short8;
typedef __attribute__((ext_vector_type(4))) float f32x4;
typedef __attribute__((ext_vector_type(4))) unsigned short bfx4;

// ---- workspace layout (bytes) ----
#define OFF_XP   0UL             // B_SZ*PSEQ*DIN*2      = 16,908,288
#define OFF_UB   16908288UL      // RTOT*SDIM*2 (bf16)   = 33,554,432
#define OFF_HS   50462720UL      // RTOT*SDIM*2 (bf16)   = 33,554,432
#define OFF_BT   84017152UL      // SDIM*DIN*2           = 1,048,576
#define OFF_CT   85065728UL      // DOUT*SDIM*2          = 1,048,576
#define OFF_MT   86114304UL      // KX*DOUT*DIN*2        = 5,242,880

__device__ __forceinline__ short f2bf(float f) {
  unsigned u = __builtin_bit_cast(unsigned, f);
  u += 0x7fffu + ((u >> 16) & 1u);   // RNE
  return (short)(u >> 16);
}
__device__ __forceinline__ float bf2f(unsigned short b) {
  return __builtin_bit_cast(float, (unsigned)b << 16);
}

#define GLOAD16(gp, lp) __builtin_amdgcn_global_load_lds( \
    (const __attribute__((address_space(1))) void*)(gp), \
    (__attribute__((address_space(3))) void*)(lp), 16, 0, 0)
#define WAITVM(n) asm volatile("s_waitcnt vmcnt(" #n ")" ::: "memory")
#define SBAR() __builtin_amdgcn_s_barrier()

// ================= conversion / prep =================
__global__ void k_conv_x(const float* __restrict__ in, short* __restrict__ out) {
  const int NG = RTOT * (DIN / 8);
  for (int g = blockIdx.x * 256 + threadIdx.x; g < NG; g += 2048 * 256) {
    int r = g >> 6, c8 = g & 63;
    int b = r >> 11, t = r & 2047;
    const float4* p = reinterpret_cast<const float4*>(in) + (size_t)g * 2;
    float4 f0 = p[0], f1 = p[1];
    short8 o;
    o[0]=f2bf(f0.x); o[1]=f2bf(f0.y); o[2]=f2bf(f0.z); o[3]=f2bf(f0.w);
    o[4]=f2bf(f1.x); o[5]=f2bf(f1.y); o[6]=f2bf(f1.z); o[7]=f2bf(f1.w);
    *reinterpret_cast<short8*>(out + ((size_t)(b * PSEQ + 16 + t) * DIN + c8 * 8)) = o;
  }
}

__global__ void k_zero_pad(short* __restrict__ Xp) {
  int idx = blockIdx.x * 256 + threadIdx.x;
  if (idx >= B_SZ * 16 * (DIN / 8)) return;
  int b = idx >> 10, rem = idx & 1023;
  int row16 = rem >> 6, c8 = rem & 63;
  const short8 z = {0,0,0,0,0,0,0,0};
  *reinterpret_cast<short8*>(Xp + ((size_t)(b * PSEQ + row16) * DIN + c8 * 8)) = z;
}

__global__ void k_transpose_bf16(const float* __restrict__ in, short* __restrict__ out,
                                 int rows, int cols) {
  __shared__ float t[32][33];
  int bx = blockIdx.x * 32, by = blockIdx.y * 32;
  int tx = threadIdx.x & 31, ty = threadIdx.x >> 5;
  #pragma unroll
  for (int j = 0; j < 32; j += 8)
    t[ty + j][tx] = in[(size_t)(by + ty + j) * cols + (bx + tx)];
  __syncthreads();
  #pragma unroll
  for (int j = 0; j < 32; j += 8)
    out[(size_t)(bx + ty + j) * rows + (by + tx)] = f2bf(t[tx][ty + j]);
}

__global__ void k_prep_M(const float* __restrict__ M, short* __restrict__ Mt) {
  int idx = blockIdx.x * 256 + threadIdx.x;
  if (idx >= DOUT * DIN) return;
  int o = idx / DIN, i = idx - o * DIN;
  const float* src = M + ((size_t)o * DIN + i) * KX;
  #pragma unroll
  for (int t = 0; t < KX; ++t)
    Mt[((size_t)t * DOUT + o) * DIN + i] = f2bf(src[t]);
}

// ================= chunked scan (uB is bf16) =================
__global__ void k_scan_E(const short* __restrict__ uB, const float* __restrict__ A,
                         float* __restrict__ E) {
  int blk = blockIdx.x, tid = threadIdx.x;
  int b = blk >> 5, c = blk & 31;
  int s0 = tid * 4;
  const short* base = uB + ((size_t)b * SEQ + (size_t)c * LC) * SDIM + s0;
  float a[4], h[4];
  #pragma unroll
  for (int j = 0; j < 4; ++j) { a[j] = A[s0 + j]; h[j] = 0.f; }
  for (int t = 0; t < LC; ++t) {
    bfx4 v = *reinterpret_cast<const bfx4*>(base + (size_t)t * SDIM);
    #pragma unroll
    for (int j = 0; j < 4; ++j) h[j] = fmaf(a[j], h[j], bf2f(v[j]));
  }
  float* ep = E + (size_t)blk * SDIM + s0;
  #pragma unroll
  for (int j = 0; j < 4; ++j) ep[j] = h[j];
}

__global__ void k_scan_S(const float* __restrict__ E, const float* __restrict__ A,
                         const float* __restrict__ h0, float* __restrict__ Sb) {
  int blk = blockIdx.x, tid = threadIdx.x;
  int b = blk >> 2;
  int s = ((blk & 3) << 8) + tid;
  float a = A[s], ap = a;
  #pragma unroll
  for (int q = 0; q < 6; ++q) ap *= ap;   // a^64
  float S = h0[s];
  for (int c = 0; c < NC; ++c) {
    size_t idx = ((size_t)b * NC + c) * SDIM + s;
    Sb[idx] = S;
    S = fmaf(ap, S, E[idx]);
  }
}

__global__ void k_scan_h(const short* __restrict__ uB, const float* __restrict__ A,
                         const float* __restrict__ Sb, short* __restrict__ hs) {
  int blk = blockIdx.x, tid = threadIdx.x;
  int b = blk >> 5, c = blk & 31;
  int s0 = tid * 4;
  const short* base = uB + ((size_t)b * SEQ + (size_t)c * LC) * SDIM + s0;
  short* hbase = hs + ((size_t)b * SEQ + (size_t)c * LC) * SDIM + s0;
  float a[4], h[4];
  #pragma unroll
  for (int j = 0; j < 4; ++j) {
    a[j] = A[s0 + j];
    h[j] = Sb[(size_t)blk * SDIM + s0 + j];
  }
  for (int t = 0; t < LC; ++t) {
    bfx4 v = *reinterpret_cast<const bfx4*>(base + (size_t)t * SDIM);
    bfx4 o;
    #pragma unroll
    for (int j = 0; j < 4; ++j) {
      h[j] = fmaf(a[j], h[j], bf2f(v[j]));
      o[j] = (unsigned short)f2bf(h[j]);
    }
    *reinterpret_cast<bfx4*>(hbase + (size_t)t * SDIM) = o;
  }
}

// ================= GEMM1: 128x128, 4 waves, dbuf + counted vmcnt (proven) ====
__device__ __forceinline__ void stage128(const short* __restrict__ g, int ld,
                                         short* l, int tid) {
  int rsub = tid >> 3;
  int slot = (tid & 7) ^ (rsub & 7);
  #pragma unroll
  for (int i = 0; i < 4; ++i) {
    int row = i * 32 + rsub;
    GLOAD16(g + (size_t)row * ld + slot * 8, l + row * 64 + (tid & 7) * 8);
  }
}

__device__ __forceinline__ void mfma_tile(const short* lA, int aoff, const short* lB,
                                          int lane, int wm, int wn, f32x4 acc[4][4]) {
  int lr = lane & 15;
  int h  = lane >> 4;
  #pragma unroll
  for (int kk = 0; kk < 2; ++kk) {
    int kslot = kk * 4 + h;
    short8 af[4], bfr[4];
    #pragma unroll
    for (int mi = 0; mi < 4; ++mi) {
      int row = aoff + wm * 64 + mi * 16 + lr;
      af[mi] = *reinterpret_cast<const short8*>(lA + row * 64 + ((kslot ^ (row & 7)) << 3));
    }
    #pragma unroll
    for (int ni = 0; ni < 4; ++ni) {
      int row = wn * 64 + ni * 16 + lr;
      bfr[ni] = *reinterpret_cast<const short8*>(lB + row * 64 + ((kslot ^ (row & 7)) << 3));
    }
    __builtin_amdgcn_s_setprio(1);
    #pragma unroll
    for (int mi = 0; mi < 4; ++mi)
      #pragma unroll
      for (int ni = 0; ni < 4; ++ni)
        acc[mi][ni] = __builtin_amdgcn_mfma_f32_16x16x32_bf16(af[mi], bfr[ni], acc[mi][ni], 0, 0, 0);
    __builtin_amdgcn_s_setprio(0);
  }
}

__global__ __launch_bounds__(256) void k_gemm_uB(const short* __restrict__ Xp,
                                                 const short* __restrict__ Bt,
                                                 short* __restrict__ uB) {
  __shared__ __attribute__((aligned(16))) short lds[32768];
  short* A0 = lds;         short* B0 = lds + 8192;
  short* A1 = lds + 16384; short* B1 = lds + 24576;
  int tid = threadIdx.x, lane = tid & 63, w = tid >> 6, wm = w >> 1, wn = w & 1;
  long r0 = (long)blockIdx.x * 128;
  int  c0 = blockIdx.y * 128;
  int  b  = (int)(r0 >> 11);
  const short* Abase = Xp + (size_t)(r0 + 16 * (b + 1)) * DIN;
  const short* Bbase = Bt + (size_t)c0 * DIN;
  const f32x4 z4 = {0.f, 0.f, 0.f, 0.f};
  f32x4 acc[4][4];
  #pragma unroll
  for (int mi = 0; mi < 4; ++mi)
    #pragma unroll
    for (int ni = 0; ni < 4; ++ni) acc[mi][ni] = z4;

  stage128(Abase, DIN, A0, tid);      stage128(Bbase, DIN, B0, tid);
  stage128(Abase + 64, DIN, A1, tid); stage128(Bbase + 64, DIN, B1, tid);
  WAITVM(8);
  SBAR();
  for (int kt = 0; kt < 8; ++kt) {
    const short* a  = (kt & 1) ? A1 : A0;
    const short* bb = (kt & 1) ? B1 : B0;
    mfma_tile(a, 0, bb, lane, wm, wn, acc);
    SBAR();
    if (kt + 2 < 8) {
      short* ad = (kt & 1) ? A1 : A0;
      short* bd = (kt & 1) ? B1 : B0;
      stage128(Abase + (kt + 2) * 64, DIN, ad, tid);
      stage128(Bbase + (kt + 2) * 64, DIN, bd, tid);
      WAITVM(8);
    } else {
      WAITVM(0);
    }
    SBAR();
  }
  #pragma unroll
  for (int mi = 0; mi < 4; ++mi)
    #pragma unroll
    for (int ni = 0; ni < 4; ++ni)
      #pragma unroll
      for (int r = 0; r < 4; ++r) {
        long row = r0 + wm * 64 + mi * 16 + (lane >> 4) * 4 + r;
        int  col = c0 + wn * 64 + ni * 16 + (lane & 15);
        uB[(size_t)row * SDIM + col] = f2bf(acc[mi][ni][r]);
      }
}

// ================= GEMM2: 256x256 tile, split-K, 8 waves of 128x64 ==========
// LDS (shorts): A0[0,16384) B0[16384,32768) A1[32768,49152) B1[49152,65536)
// Phase2: Xs[0,17408) (A0 + head of B0), M0 = A1 region, M1 = B1 region.

__device__ __forceinline__ void stage256(const short* __restrict__ g, int ld,
                                         short* l, int tid) {
  int rsub = tid >> 3;                      // 0..63 (512 threads)
  int slot = (tid & 7) ^ (rsub & 7);        // pre-swizzled 16B slot
  #pragma unroll
  for (int i = 0; i < 4; ++i) {
    int row = i * 64 + rsub;
    GLOAD16(g + (size_t)row * ld + slot * 8, l + row * 64 + (tid & 7) * 8);
  }
}
__device__ __forceinline__ void stageX272(const short* __restrict__ g, int ld,
                                          short* l, int tid) {
  stage256(g, ld, l, tid);
  if (tid < 128) {
    int rsub = tid >> 3;
    int row = 256 + rsub;
    int slot = (tid & 7) ^ (row & 7);
    GLOAD16(g + (size_t)row * ld + slot * 8, l + row * 64 + (tid & 7) * 8);
  }
}

// one K=64 step; wave out = 128x64 (mi 0..7, ni 0..3)
__device__ __forceinline__ void compute_step2(const short* la, int aoff, const short* lb,
                                              int lane, int wm, int wn, f32x4 acc[8][4]) {
  int lr = lane & 15;
  int h  = lane >> 4;
  #pragma unroll
  for (int kk = 0; kk < 2; ++kk) {
    int kslot = kk * 4 + h;
    short8 af[8], bfr[4];
    #pragma unroll
    for (int ni = 0; ni < 4; ++ni) {
      int row = wn * 64 + ni * 16 + lr;
      bfr[ni] = *reinterpret_cast<const short8*>(lb + row * 64 + ((kslot ^ (row & 7)) << 3));
    }
    #pragma unroll
    for (int mi = 0; mi < 8; ++mi) {
      int row = aoff + wm * 128 + mi * 16 + lr;
      af[mi] = *reinterpret_cast<const short8*>(la + row * 64 + ((kslot ^ (row & 7)) << 3));
    }
    __builtin_amdgcn_s_setprio(1);
    #pragma unroll
    for (int mi = 0; mi < 8; ++mi)
      #pragma unroll
      for (int ni = 0; ni < 4; ++ni)
        acc[mi][ni] = __builtin_amdgcn_mfma_f32_16x16x32_bf16(af[mi], bfr[ni], acc[mi][ni], 0, 0, 0);
    __builtin_amdgcn_s_setprio(0);
  }
}

__global__ __launch_bounds__(512) void k_gemm_out(const short* __restrict__ hs,
                                                  const short* __restrict__ Xp,
                                                  const short* __restrict__ Ct,
                                                  const short* __restrict__ Mt,
                                                  float* __restrict__ out) {
  __shared__ __attribute__((aligned(16))) short lds[65536];
  short* A0p = lds;          short* B0p = lds + 16384;
  short* A1p = lds + 32768;  short* B1p = lds + 49152;
  short* Xs  = lds;
  short* M0p = lds + 32768;  short* M1p = lds + 49152;
  int tid = threadIdx.x, lane = tid & 63, w = tid >> 6;
  int wm = w & 1, wn = w >> 1;                  // 2M x 4N waves, 128x64 each
  // XCD swizzle: each XCD serves one (c0, khalf) B-panel (~1.5 MB, L2-fits)
  int bid = blockIdx.x;
  int sw  = (bid & 7) * 32 + (bid >> 3);        // bijective over 256
  int rowblk = sw & 63, combo = sw >> 6;        // 64 rowblks x 4 combos
  long r0 = (long)rowblk * 256;
  int  c0 = (combo & 1) * 256;
  int  khalf = combo >> 1;
  int  b  = (int)(r0 >> 11);
  const short* hsA = hs + (size_t)r0 * SDIM;
  const short* CtB = Ct + (size_t)c0 * SDIM;
  const short* Xa  = Xp + (size_t)(r0 + 16 * (b + 1) - 16) * DIN;
  const short* MtB = Mt + (size_t)c0 * DIN;

  const f32x4 z4 = {0.f, 0.f, 0.f, 0.f};
  f32x4 acc[8][4];
  #pragma unroll
  for (int mi = 0; mi < 8; ++mi)
    #pragma unroll
    for (int ni = 0; ni < 4; ++ni) acc[mi][ni] = z4;

  int tap_lo, tap_hi;   // conv taps handled by this half
  if (khalf == 0) {
    tap_lo = 0; tap_hi = 3;
    // ---- phase 1: hs @ Ct^T, K = 1024 (16 steps) ----
    stage256(hsA, SDIM, A0p, tid);
    stage256(CtB, SDIM, B0p, tid);
    WAITVM(0);
    SBAR();
    for (int s = 0; s < 16; ++s) {
      const short* la = (s & 1) ? A1p : A0p;
      const short* lb = (s & 1) ? B1p : B0p;
      short* na = (s & 1) ? A0p : A1p;
      short* nb = (s & 1) ? B0p : B1p;
      if (s + 1 < 16) {
        stage256(hsA + (s + 1) * 64, SDIM, na, tid);
        stage256(CtB + (s + 1) * 64, SDIM, nb, tid);
      } else {
        stageX272(Xa, DIN, Xs, tid);   // s=15 computes A1/B1; Xs = A0/B0 region
      }
      compute_step2(la, 0, lb, lane, wm, wn, acc);
      WAITVM(0);
      SBAR();
    }
    stage256(MtB, DIN, M0p, tid);      // tap 0, slice 0 (M0 = A1 region, now free)
    WAITVM(0);
    SBAR();
  } else {
    tap_lo = 4; tap_hi = 9;
    stageX272(Xa, DIN, Xs, tid);
    stage256(MtB + (size_t)4 * DOUT * DIN, DIN, M0p, tid);
    WAITVM(0);
    SBAR();
  }

  // ---- phase 2: AR conv taps [tap_lo..tap_hi], Xs reused per k0-slice ----
  for (int k0 = 0; k0 < 8; ++k0) {
    int kc = k0 * 64;
    for (int j = 0; j <= tap_hi - tap_lo; ++j) {
      int tap = tap_lo + j;
      const short* lm = (j & 1) ? M1p : M0p;
      short* nm = (j & 1) ? M0p : M1p;
      if (tap < tap_hi)
        stage256(MtB + (size_t)(tap + 1) * DOUT * DIN + kc, DIN, nm, tid);
      else if (k0 + 1 < 8)
        stage256(MtB + (size_t)tap_lo * DOUT * DIN + kc + 64, DIN, nm, tid);
      compute_step2(Xs, 16 - tap, lm, lane, wm, wn, acc);
      WAITVM(0);
      SBAR();
    }
    if (k0 + 1 < 8) {
      stageX272(Xa + kc + 64, DIN, Xs, tid);
      WAITVM(0);
      SBAR();
    }
  }

  // ---- epilogue: atomic accumulate (out pre-zeroed on stream) ----
  #pragma unroll
  for (int mi = 0; mi < 8; ++mi)
    #pragma unroll
    for (int ni = 0; ni < 4; ++ni)
      #pragma unroll
      for (int r = 0; r < 4; ++r) {
        long row = r0 + wm * 128 + mi * 16 + (lane >> 4) * 4 + r;
        int  col = c0 + wn * 64 + ni * 16 + (lane & 15);
        atomicAdd(&out[(size_t)row * DOUT + col], acc[mi][ni][r]);
      }
}

// ================= launch =================
extern "C" void kernel_launch(void* const* d_in, const int* in_sizes, int n_in,
                              void* d_out, int out_size, void* d_ws, size_t ws_size,
                              hipStream_t stream) {
  (void)in_sizes; (void)n_in; (void)out_size; (void)ws_size;
  const float* x  = (const float*)d_in[0];
  const float* h0 = (const float*)d_in[1];
  const float* A  = (const float*)d_in[2];
  const float* B  = (const float*)d_in[3];
  const float* C  = (const float*)d_in[4];
  const float* M  = (const float*)d_in[5];
  float* out = (float*)d_out;
  char* ws = (char*)d_ws;

  short* Xp  = (short*)(ws + OFF_XP);
  short* uB  = (short*)(ws + OFF_UB);
  short* hsb = (short*)(ws + OFF_HS);
  short* Bt  = (short*)(ws + OFF_BT);
  short* Ct  = (short*)(ws + OFF_CT);
  short* Mt  = (short*)(ws + OFF_MT);
  // scan scratch inside d_out (consumed before the pre-GEMM2 memset)
  float* E   = out;                    // B_SZ*NC*SDIM f32 = 1 MiB
  float* Sb  = out + B_SZ * NC * SDIM; // 1 MiB

  k_conv_x<<<2048, 256, 0, stream>>>(x, Xp);
  k_zero_pad<<<32, 256, 0, stream>>>(Xp);
  k_transpose_bf16<<<dim3(SDIM / 32, DIN / 32), 256, 0, stream>>>(B, Bt, DIN, SDIM);
  k_transpose_bf16<<<dim3(DOUT / 32, SDIM / 32), 256, 0, stream>>>(C, Ct, SDIM, DOUT);
  k_prep_M<<<(DOUT * DIN + 255) / 256, 256, 0, stream>>>(M, Mt);

  k_gemm_uB<<<dim3(RTOT / 128, SDIM / 128), 256, 0, stream>>>(Xp, Bt, uB);

  k_scan_E<<<B_SZ * NC, 256, 0, stream>>>(uB, A, E);
  k_scan_S<<<B_SZ * 4, 256, 0, stream>>>(E, A, h0, Sb);
  k_scan_h<<<B_SZ * NC, 256, 0, stream>>>(uB, A, Sb, hsb);

  // zero out for split-K atomic accumulation (E/Sb already consumed)
  hipMemsetAsync(out, 0, (size_t)RTOT * DOUT * sizeof(float), stream);

  k_gemm_out<<<256, 512, 0, stream>>>(hsb, Xp, Ct, Mt, out);
}

// Round 9
// 155.964 us; speedup vs baseline: 1.2913x; 1.2913x over previous
//
#include <hip/hip_runtime.h>

#define B_SZ   8
#define SEQ    2048
#define PSEQ   (SEQ+16)     // 16 zero pad rows before each batch
#define SDIM   1024
#define DIN    512
#define DOUT   512
#define KX     10
#define RTOT   (B_SZ*SEQ)   // 16384
#define LC     64
#define NC     (SEQ/LC)     // 32

typedef __attribute__((ext_vector_type(8))) short short8;
typedef __attribute__((ext_vector_type(4))) float f32x4;
typedef __attribute__((ext_vector_type(4))) unsigned short bfx4;

// ---- workspace layout (bytes) ----
#define OFF_XP   0UL             // B_SZ*PSEQ*DIN*2      = 16,908,288
#define OFF_UB   16908288UL      // RTOT*SDIM*2 (bf16)   = 33,554,432
#define OFF_HS   50462720UL      // RTOT*SDIM*2 (bf16)   = 33,554,432
#define OFF_BT   84017152UL      // SDIM*DIN*2           = 1,048,576
#define OFF_CT   85065728UL      // DOUT*SDIM*2          = 1,048,576
#define OFF_MT   86114304UL      // KX*DOUT*DIN*2        = 5,242,880

__device__ __forceinline__ short f2bf(float f) {
  unsigned u = __builtin_bit_cast(unsigned, f);
  u += 0x7fffu + ((u >> 16) & 1u);   // RNE
  return (short)(u >> 16);
}
__device__ __forceinline__ float bf2f(unsigned short b) {
  return __builtin_bit_cast(float, (unsigned)b << 16);
}

#define GLOAD16(gp, lp) __builtin_amdgcn_global_load_lds( \
    (const __attribute__((address_space(1))) void*)(gp), \
    (__attribute__((address_space(3))) void*)(lp), 16, 0, 0)
#define WAITVM(n) asm volatile("s_waitcnt vmcnt(" #n ")" ::: "memory")
#define SBAR() __builtin_amdgcn_s_barrier()

// ================= conversion / prep =================
__global__ void k_conv_x(const float* __restrict__ in, short* __restrict__ out) {
  const int NG = RTOT * (DIN / 8);
  for (int g = blockIdx.x * 256 + threadIdx.x; g < NG; g += 2048 * 256) {
    int r = g >> 6, c8 = g & 63;
    int b = r >> 11, t = r & 2047;
    const float4* p = reinterpret_cast<const float4*>(in) + (size_t)g * 2;
    float4 f0 = p[0], f1 = p[1];
    short8 o;
    o[0]=f2bf(f0.x); o[1]=f2bf(f0.y); o[2]=f2bf(f0.z); o[3]=f2bf(f0.w);
    o[4]=f2bf(f1.x); o[5]=f2bf(f1.y); o[6]=f2bf(f1.z); o[7]=f2bf(f1.w);
    *reinterpret_cast<short8*>(out + ((size_t)(b * PSEQ + 16 + t) * DIN + c8 * 8)) = o;
  }
}

__global__ void k_zero_pad(short* __restrict__ Xp) {
  int idx = blockIdx.x * 256 + threadIdx.x;
  if (idx >= B_SZ * 16 * (DIN / 8)) return;
  int b = idx >> 10, rem = idx & 1023;
  int row16 = rem >> 6, c8 = rem & 63;
  const short8 z = {0,0,0,0,0,0,0,0};
  *reinterpret_cast<short8*>(Xp + ((size_t)(b * PSEQ + row16) * DIN + c8 * 8)) = z;
}

__global__ void k_transpose_bf16(const float* __restrict__ in, short* __restrict__ out,
                                 int rows, int cols) {
  __shared__ float t[32][33];
  int bx = blockIdx.x * 32, by = blockIdx.y * 32;
  int tx = threadIdx.x & 31, ty = threadIdx.x >> 5;
  #pragma unroll
  for (int j = 0; j < 32; j += 8)
    t[ty + j][tx] = in[(size_t)(by + ty + j) * cols + (bx + tx)];
  __syncthreads();
  #pragma unroll
  for (int j = 0; j < 32; j += 8)
    out[(size_t)(bx + ty + j) * rows + (by + tx)] = f2bf(t[tx][ty + j]);
}

__global__ void k_prep_M(const float* __restrict__ M, short* __restrict__ Mt) {
  int idx = blockIdx.x * 256 + threadIdx.x;
  if (idx >= DOUT * DIN) return;
  int o = idx / DIN, i = idx - o * DIN;
  const float* src = M + ((size_t)o * DIN + i) * KX;
  #pragma unroll
  for (int t = 0; t < KX; ++t)
    Mt[((size_t)t * DOUT + o) * DIN + i] = f2bf(src[t]);
}

// ================= chunked scan (uB is bf16) =================
__global__ void k_scan_E(const short* __restrict__ uB, const float* __restrict__ A,
                         float* __restrict__ E) {
  int blk = blockIdx.x, tid = threadIdx.x;
  int b = blk >> 5, c = blk & 31;
  int s0 = tid * 4;
  const short* base = uB + ((size_t)b * SEQ + (size_t)c * LC) * SDIM + s0;
  float a[4], h[4];
  #pragma unroll
  for (int j = 0; j < 4; ++j) { a[j] = A[s0 + j]; h[j] = 0.f; }
  for (int t = 0; t < LC; ++t) {
    bfx4 v = *reinterpret_cast<const bfx4*>(base + (size_t)t * SDIM);
    #pragma unroll
    for (int j = 0; j < 4; ++j) h[j] = fmaf(a[j], h[j], bf2f(v[j]));
  }
  float* ep = E + (size_t)blk * SDIM + s0;
  #pragma unroll
  for (int j = 0; j < 4; ++j) ep[j] = h[j];
}

__global__ void k_scan_S(const float* __restrict__ E, const float* __restrict__ A,
                         const float* __restrict__ h0, float* __restrict__ Sb) {
  int blk = blockIdx.x, tid = threadIdx.x;
  int b = blk >> 2;
  int s = ((blk & 3) << 8) + tid;
  float a = A[s], ap = a;
  #pragma unroll
  for (int q = 0; q < 6; ++q) ap *= ap;   // a^64
  float S = h0[s];
  for (int c = 0; c < NC; ++c) {
    size_t idx = ((size_t)b * NC + c) * SDIM + s;
    Sb[idx] = S;
    S = fmaf(ap, S, E[idx]);
  }
}

__global__ void k_scan_h(const short* __restrict__ uB, const float* __restrict__ A,
                         const float* __restrict__ Sb, short* __restrict__ hs) {
  int blk = blockIdx.x, tid = threadIdx.x;
  int b = blk >> 5, c = blk & 31;
  int s0 = tid * 4;
  const short* base = uB + ((size_t)b * SEQ + (size_t)c * LC) * SDIM + s0;
  short* hbase = hs + ((size_t)b * SEQ + (size_t)c * LC) * SDIM + s0;
  float a[4], h[4];
  #pragma unroll
  for (int j = 0; j < 4; ++j) {
    a[j] = A[s0 + j];
    h[j] = Sb[(size_t)blk * SDIM + s0 + j];
  }
  for (int t = 0; t < LC; ++t) {
    bfx4 v = *reinterpret_cast<const bfx4*>(base + (size_t)t * SDIM);
    bfx4 o;
    #pragma unroll
    for (int j = 0; j < 4; ++j) {
      h[j] = fmaf(a[j], h[j], bf2f(v[j]));
      o[j] = (unsigned short)f2bf(h[j]);
    }
    *reinterpret_cast<bfx4*>(hbase + (size_t)t * SDIM) = o;
  }
}

// ================= GEMM1: 128x128, 4 waves, dbuf + counted vmcnt (proven) ====
__device__ __forceinline__ void stage128(const short* __restrict__ g, int ld,
                                         short* l, int tid) {
  int rsub = tid >> 3;
  int slot = (tid & 7) ^ (rsub & 7);
  #pragma unroll
  for (int i = 0; i < 4; ++i) {
    int row = i * 32 + rsub;
    GLOAD16(g + (size_t)row * ld + slot * 8, l + row * 64 + (tid & 7) * 8);
  }
}

__device__ __forceinline__ void mfma_tile(const short* lA, int aoff, const short* lB,
                                          int lane, int wm, int wn, f32x4 acc[4][4]) {
  int lr = lane & 15;
  int h  = lane >> 4;
  #pragma unroll
  for (int kk = 0; kk < 2; ++kk) {
    int kslot = kk * 4 + h;
    short8 af[4], bfr[4];
    #pragma unroll
    for (int mi = 0; mi < 4; ++mi) {
      int row = aoff + wm * 64 + mi * 16 + lr;
      af[mi] = *reinterpret_cast<const short8*>(lA + row * 64 + ((kslot ^ (row & 7)) << 3));
    }
    #pragma unroll
    for (int ni = 0; ni < 4; ++ni) {
      int row = wn * 64 + ni * 16 + lr;
      bfr[ni] = *reinterpret_cast<const short8*>(lB + row * 64 + ((kslot ^ (row & 7)) << 3));
    }
    __builtin_amdgcn_s_setprio(1);
    #pragma unroll
    for (int mi = 0; mi < 4; ++mi)
      #pragma unroll
      for (int ni = 0; ni < 4; ++ni)
        acc[mi][ni] = __builtin_amdgcn_mfma_f32_16x16x32_bf16(af[mi], bfr[ni], acc[mi][ni], 0, 0, 0);
    __builtin_amdgcn_s_setprio(0);
  }
}

__global__ __launch_bounds__(256) void k_gemm_uB(const short* __restrict__ Xp,
                                                 const short* __restrict__ Bt,
                                                 short* __restrict__ uB) {
  __shared__ __attribute__((aligned(16))) short lds[32768];
  short* A0 = lds;         short* B0 = lds + 8192;
  short* A1 = lds + 16384; short* B1 = lds + 24576;
  int tid = threadIdx.x, lane = tid & 63, w = tid >> 6, wm = w >> 1, wn = w & 1;
  long r0 = (long)blockIdx.x * 128;
  int  c0 = blockIdx.y * 128;
  int  b  = (int)(r0 >> 11);
  const short* Abase = Xp + (size_t)(r0 + 16 * (b + 1)) * DIN;
  const short* Bbase = Bt + (size_t)c0 * DIN;
  const f32x4 z4 = {0.f, 0.f, 0.f, 0.f};
  f32x4 acc[4][4];
  #pragma unroll
  for (int mi = 0; mi < 4; ++mi)
    #pragma unroll
    for (int ni = 0; ni < 4; ++ni) acc[mi][ni] = z4;

  stage128(Abase, DIN, A0, tid);      stage128(Bbase, DIN, B0, tid);
  stage128(Abase + 64, DIN, A1, tid); stage128(Bbase + 64, DIN, B1, tid);
  WAITVM(8);
  SBAR();
  for (int kt = 0; kt < 8; ++kt) {
    const short* a  = (kt & 1) ? A1 : A0;
    const short* bb = (kt & 1) ? B1 : B0;
    mfma_tile(a, 0, bb, lane, wm, wn, acc);
    SBAR();
    if (kt + 2 < 8) {
      short* ad = (kt & 1) ? A1 : A0;
      short* bd = (kt & 1) ? B1 : B0;
      stage128(Abase + (kt + 2) * 64, DIN, ad, tid);
      stage128(Bbase + (kt + 2) * 64, DIN, bd, tid);
      WAITVM(8);
    } else {
      WAITVM(0);
    }
    SBAR();
  }
  #pragma unroll
  for (int mi = 0; mi < 4; ++mi)
    #pragma unroll
    for (int ni = 0; ni < 4; ++ni)
      #pragma unroll
      for (int r = 0; r < 4; ++r) {
        long row = r0 + wm * 64 + mi * 16 + (lane >> 4) * 4 + r;
        int  col = c0 + wn * 64 + ni * 16 + (lane & 15);
        uB[(size_t)row * SDIM + col] = f2bf(acc[mi][ni][r]);
      }
}

// ================= GEMM2: 256x128, 8 waves, cross-barrier counted vmcnt ======
// LDS (shorts, 51200 total = 100 KB):
//  phase1: A0[0,16384) B0[16384,24576) A1[24576,40960) B1[40960,49152)
//  phase2: Xs0[0,17408) Xs1[17408,34816) M0[34816,43008) M1[43008,51200)
// Per-tile loads/thread: phase1 = 6 (A4+B2), phase2 M = 2, X = 4 or 5.

__device__ __forceinline__ void stageA256(const short* __restrict__ g, int ld,
                                          short* l, int tid) {
  int rsub = tid >> 3;
  int slot = (tid & 7) ^ (rsub & 7);
  #pragma unroll
  for (int i = 0; i < 4; ++i) {
    int row = i * 64 + rsub;
    GLOAD16(g + (size_t)row * ld + slot * 8, l + row * 64 + (tid & 7) * 8);
  }
}
__device__ __forceinline__ void stageB128(const short* __restrict__ g, int ld,
                                          short* l, int tid) {
  int rsub = tid >> 3;
  int slot = (tid & 7) ^ (rsub & 7);
  #pragma unroll
  for (int i = 0; i < 2; ++i) {
    int row = i * 64 + rsub;
    GLOAD16(g + (size_t)row * ld + slot * 8, l + row * 64 + (tid & 7) * 8);
  }
}
__device__ __forceinline__ void stageX272(const short* __restrict__ g, int ld,
                                          short* l, int tid) {
  stageA256(g, ld, l, tid);
  if (tid < 128) {
    int rsub = tid >> 3;
    int row = 256 + rsub;
    int slot = (tid & 7) ^ (row & 7);
    GLOAD16(g + (size_t)row * ld + slot * 8, l + row * 64 + (tid & 7) * 8);
  }
}

// one K=64 step: per wave 64x64 out (mi,ni 0..3)
__device__ __forceinline__ void compute_step(const short* la, int aoff, const short* lb,
                                             int lane, int wm, int wn, f32x4 acc[4][4]) {
  int lr = lane & 15;
  int h  = lane >> 4;
  short8 af[4][2], bfr[4][2];
  #pragma unroll
  for (int kk = 0; kk < 2; ++kk) {
    int kslot = kk * 4 + h;
    #pragma unroll
    for (int mi = 0; mi < 4; ++mi) {
      int row = aoff + wm * 64 + mi * 16 + lr;
      af[mi][kk] = *reinterpret_cast<const short8*>(la + row * 64 + ((kslot ^ (row & 7)) << 3));
    }
    #pragma unroll
    for (int ni = 0; ni < 4; ++ni) {
      int row = wn * 64 + ni * 16 + lr;
      bfr[ni][kk] = *reinterpret_cast<const short8*>(lb + row * 64 + ((kslot ^ (row & 7)) << 3));
    }
  }
  __builtin_amdgcn_s_setprio(1);
  #pragma unroll
  for (int kk = 0; kk < 2; ++kk)
    #pragma unroll
    for (int mi = 0; mi < 4; ++mi)
      #pragma unroll
      for (int ni = 0; ni < 4; ++ni)
        acc[mi][ni] = __builtin_amdgcn_mfma_f32_16x16x32_bf16(af[mi][kk], bfr[ni][kk], acc[mi][ni], 0, 0, 0);
  __builtin_amdgcn_s_setprio(0);
}

__global__ __launch_bounds__(512) void k_gemm_out(const short* __restrict__ hs,
                                                  const short* __restrict__ Xp,
                                                  const short* __restrict__ Ct,
                                                  const short* __restrict__ Mt,
                                                  float* __restrict__ out) {
  __shared__ __attribute__((aligned(16))) short lds[51200];
  short* A0p = lds;          short* B0p = lds + 16384;
  short* A1p = lds + 24576;  short* B1p = lds + 40960;
  short* Xs0 = lds;          short* Xs1 = lds + 17408;
  short* M0p = lds + 34816;  short* M1p = lds + 43008;
  int tid = threadIdx.x, lane = tid & 63, w = tid >> 6;
  int wm = w >> 1, wn = w & 1;                  // 4M x 2N waves, 64x64 each
  int bid = blockIdx.x;
  int sw  = (bid & 7) * 32 + (bid >> 3);        // bijective over 256
  long r0 = (long)(sw & 63) * 256;
  int  c0 = (sw >> 6) * 128;
  int  b  = (int)(r0 >> 11);
  const short* hsA = hs + (size_t)r0 * SDIM;
  const short* CtB = Ct + (size_t)c0 * SDIM;
  const short* Xa  = Xp + (size_t)(r0 + 16 * (b + 1) - 16) * DIN;
  const short* MtB = Mt + (size_t)c0 * DIN;

  const f32x4 z4 = {0.f, 0.f, 0.f, 0.f};
  f32x4 acc[4][4];
  #pragma unroll
  for (int mi = 0; mi < 4; ++mi)
    #pragma unroll
    for (int ni = 0; ni < 4; ++ni) acc[mi][ni] = z4;

  // ---- phase 1: hs @ Ct^T, K = 1024, 16 steps, counted vmcnt(6) ----
  stageA256(hsA, SDIM, A0p, tid);
  stageB128(CtB, SDIM, B0p, tid);
  stageA256(hsA + 64, SDIM, A1p, tid);
  stageB128(CtB + 64, SDIM, B1p, tid);
  WAITVM(6);          // tile 0 landed; tile 1's 6 loads in flight
  SBAR();
  for (int s = 0; s < 16; ++s) {
    const short* la = (s & 1) ? A1p : A0p;
    const short* lb = (s & 1) ? B1p : B0p;
    compute_step(la, 0, lb, lane, wm, wn, acc);
    SBAR();                                   // all waves done reading buf[s&1]
    if (s + 2 < 16) {
      short* na = (s & 1) ? A1p : A0p;        // refill freed buffer
      short* nb = (s & 1) ? B1p : B0p;
      stageA256(hsA + (s + 2) * 64, SDIM, na, tid);
      stageB128(CtB + (s + 2) * 64, SDIM, nb, tid);
      WAITVM(6);                              // tile s+1 landed; s+2 in flight
    } else if (s == 14) {
      stageX272(Xa, DIN, Xs0, tid);           // into freed A0/B0 region
      WAITVM(4);                              // tile 15 landed; X in flight
    } else { // s == 15 (A1/B1 now free; M regions overlap them)
      stageB128(MtB, DIN, M0p, tid);
      stageB128(MtB + (size_t)DOUT * DIN, DIN, M1p, tid);
      WAITVM(2);                              // Xs0 + M0 landed; M1 in flight
    }
    SBAR();
  }

  // ---- phase 2: AR conv, X dbuf (slice-ahead), Mt dbuf, counted vmcnt ----
  for (int k0 = 0; k0 < 8; ++k0) {
    const short* xs = (k0 & 1) ? Xs1 : Xs0;
    short*       xn = (k0 & 1) ? Xs0 : Xs1;
    int kc = k0 * 64;
    bool lastslice = (k0 == 7);
    for (int j = 0; j < KX; ++j) {
      const short* lm = (j & 1) ? M1p : M0p;
      short*       nm = (j & 1) ? M1p : M0p;  // same buffer, refilled
      compute_step(xs, 16 - j, lm, lane, wm, wn, acc);
      SBAR();
      if (j + 2 < KX)
        stageB128(MtB + (size_t)(j + 2) * DOUT * DIN + kc, DIN, nm, tid);
      else if (!lastslice)
        stageB128(MtB + (size_t)(j + 2 - KX) * DOUT * DIN + kc + 64, DIN, nm, tid);
      if (j == 1 && !lastslice)
        stageX272(Xa + kc + 64, DIN, xn, tid);   // X for slice k0+1
      if ((j == 1 || j == 2) && !lastslice) {
        WAITVM(6);          // need M(j+1); younger = M(j+2) + X(4/5)
      } else if (j + 2 < KX || !lastslice) {
        WAITVM(2);          // need M(j+1) (or next-slice M0); younger = 2
      } else {
        WAITVM(0);          // tail of last slice
      }
      SBAR();
    }
  }

  #pragma unroll
  for (int mi = 0; mi < 4; ++mi)
    #pragma unroll
    for (int ni = 0; ni < 4; ++ni)
      #pragma unroll
      for (int r = 0; r < 4; ++r) {
        long row = r0 + wm * 64 + mi * 16 + (lane >> 4) * 4 + r;
        int  col = c0 + wn * 64 + ni * 16 + (lane & 15);
        out[(size_t)row * DOUT + col] = acc[mi][ni][r];
      }
}

// ================= launch =================
extern "C" void kernel_launch(void* const* d_in, const int* in_sizes, int n_in,
                              void* d_out, int out_size, void* d_ws, size_t ws_size,
                              hipStream_t stream) {
  (void)in_sizes; (void)n_in; (void)out_size; (void)ws_size;
  const float* x  = (const float*)d_in[0];
  const float* h0 = (const float*)d_in[1];
  const float* A  = (const float*)d_in[2];
  const float* B  = (const float*)d_in[3];
  const float* C  = (const float*)d_in[4];
  const float* M  = (const float*)d_in[5];
  float* out = (float*)d_out;
  char* ws = (char*)d_ws;

  short* Xp  = (short*)(ws + OFF_XP);
  short* uB  = (short*)(ws + OFF_UB);
  short* hsb = (short*)(ws + OFF_HS);
  short* Bt  = (short*)(ws + OFF_BT);
  short* Ct  = (short*)(ws + OFF_CT);
  short* Mt  = (short*)(ws + OFF_MT);
  // scan scratch inside d_out (fully overwritten by k_gemm_out afterwards)
  float* E   = out;                    // B_SZ*NC*SDIM f32 = 1 MiB
  float* Sb  = out + B_SZ * NC * SDIM; // 1 MiB

  k_conv_x<<<2048, 256, 0, stream>>>(x, Xp);
  k_zero_pad<<<32, 256, 0, stream>>>(Xp);
  k_transpose_bf16<<<dim3(SDIM / 32, DIN / 32), 256, 0, stream>>>(B, Bt, DIN, SDIM);
  k_transpose_bf16<<<dim3(DOUT / 32, SDIM / 32), 256, 0, stream>>>(C, Ct, SDIM, DOUT);
  k_prep_M<<<(DOUT * DIN + 255) / 256, 256, 0, stream>>>(M, Mt);

  k_gemm_uB<<<dim3(RTOT / 128, SDIM / 128), 256, 0, stream>>>(Xp, Bt, uB);

  k_scan_E<<<B_SZ * NC, 256, 0, stream>>>(uB, A, E);
  k_scan_S<<<B_SZ * 4, 256, 0, stream>>>(E, A, h0, Sb);
  k_scan_h<<<B_SZ * NC, 256, 0, stream>>>(uB, A, Sb, hsb);

  k_gemm_out<<<256, 512, 0, stream>>>(hsb, Xp, Ct, Mt, out);
}

// Round 10
// 153.667 us; speedup vs baseline: 1.3106x; 1.0149x over previous
//
#include <hip/hip_runtime.h>

#define B_SZ   8
#define SEQ    2048
#define PSEQ   (SEQ+16)     // 16 zero pad rows before each batch
#define SDIM   1024
#define DIN    512
#define DOUT   512
#define KX     10
#define RTOT   (B_SZ*SEQ)   // 16384
#define LC     64
#define NC     (SEQ/LC)     // 32

typedef __attribute__((ext_vector_type(8))) short short8;
typedef __attribute__((ext_vector_type(4))) float f32x4;
typedef __attribute__((ext_vector_type(4))) unsigned short bfx4;

// ---- workspace layout (bytes). Xp has 64 slack rows for X-prefetch overread.
#define OFF_XP   0UL             // (B_SZ*PSEQ+64)*DIN*2 = 16,973,824
#define OFF_UB   16973824UL      // RTOT*SDIM*2 (bf16)   = 33,554,432
#define OFF_HS   50528256UL      // RTOT*SDIM*2 (bf16)   = 33,554,432
#define OFF_BT   84082688UL      // SDIM*DIN*2           = 1,048,576
#define OFF_CT   85131264UL      // DOUT*SDIM*2          = 1,048,576
#define OFF_MT   86179840UL      // KX*DOUT*DIN*2        = 5,242,880

__device__ __forceinline__ short f2bf(float f) {
  unsigned u = __builtin_bit_cast(unsigned, f);
  u += 0x7fffu + ((u >> 16) & 1u);   // RNE
  return (short)(u >> 16);
}
__device__ __forceinline__ float bf2f(unsigned short b) {
  return __builtin_bit_cast(float, (unsigned)b << 16);
}

#define GLOAD16(gp, lp) __builtin_amdgcn_global_load_lds( \
    (const __attribute__((address_space(1))) void*)(gp), \
    (__attribute__((address_space(3))) void*)(lp), 16, 0, 0)
#define WAITVM(n) asm volatile("s_waitcnt vmcnt(" #n ")" ::: "memory")
#define LGKM0()   do { asm volatile("s_waitcnt lgkmcnt(0)" ::: "memory"); \
                       __builtin_amdgcn_sched_barrier(0); } while (0)
#define SBAR() __builtin_amdgcn_s_barrier()

// ================= conversion / prep =================
__global__ void k_conv_x(const float* __restrict__ in, short* __restrict__ out) {
  const int NG = RTOT * (DIN / 8);
  for (int g = blockIdx.x * 256 + threadIdx.x; g < NG; g += 2048 * 256) {
    int r = g >> 6, c8 = g & 63;
    int b = r >> 11, t = r & 2047;
    const float4* p = reinterpret_cast<const float4*>(in) + (size_t)g * 2;
    float4 f0 = p[0], f1 = p[1];
    short8 o;
    o[0]=f2bf(f0.x); o[1]=f2bf(f0.y); o[2]=f2bf(f0.z); o[3]=f2bf(f0.w);
    o[4]=f2bf(f1.x); o[5]=f2bf(f1.y); o[6]=f2bf(f1.z); o[7]=f2bf(f1.w);
    *reinterpret_cast<short8*>(out + ((size_t)(b * PSEQ + 16 + t) * DIN + c8 * 8)) = o;
  }
}

__global__ void k_zero_pad(short* __restrict__ Xp) {
  int idx = blockIdx.x * 256 + threadIdx.x;
  if (idx >= B_SZ * 16 * (DIN / 8)) return;
  int b = idx >> 10, rem = idx & 1023;
  int row16 = rem >> 6, c8 = rem & 63;
  const short8 z = {0,0,0,0,0,0,0,0};
  *reinterpret_cast<short8*>(Xp + ((size_t)(b * PSEQ + row16) * DIN + c8 * 8)) = z;
}

__global__ void k_transpose_bf16(const float* __restrict__ in, short* __restrict__ out,
                                 int rows, int cols) {
  __shared__ float t[32][33];
  int bx = blockIdx.x * 32, by = blockIdx.y * 32;
  int tx = threadIdx.x & 31, ty = threadIdx.x >> 5;
  #pragma unroll
  for (int j = 0; j < 32; j += 8)
    t[ty + j][tx] = in[(size_t)(by + ty + j) * cols + (bx + tx)];
  __syncthreads();
  #pragma unroll
  for (int j = 0; j < 32; j += 8)
    out[(size_t)(bx + ty + j) * rows + (by + tx)] = f2bf(t[tx][ty + j]);
}

__global__ void k_prep_M(const float* __restrict__ M, short* __restrict__ Mt) {
  int idx = blockIdx.x * 256 + threadIdx.x;
  if (idx >= DOUT * DIN) return;
  int o = idx / DIN, i = idx - o * DIN;
  const float* src = M + ((size_t)o * DIN + i) * KX;
  #pragma unroll
  for (int t = 0; t < KX; ++t)
    Mt[((size_t)t * DOUT + o) * DIN + i] = f2bf(src[t]);
}

// ================= chunked scan (uB is bf16) =================
__global__ void k_scan_E(const short* __restrict__ uB, const float* __restrict__ A,
                         float* __restrict__ E) {
  int blk = blockIdx.x, tid = threadIdx.x;
  int b = blk >> 5, c = blk & 31;
  int s0 = tid * 4;
  const short* base = uB + ((size_t)b * SEQ + (size_t)c * LC) * SDIM + s0;
  float a[4], h[4];
  #pragma unroll
  for (int j = 0; j < 4; ++j) { a[j] = A[s0 + j]; h[j] = 0.f; }
  for (int t = 0; t < LC; ++t) {
    bfx4 v = *reinterpret_cast<const bfx4*>(base + (size_t)t * SDIM);
    #pragma unroll
    for (int j = 0; j < 4; ++j) h[j] = fmaf(a[j], h[j], bf2f(v[j]));
  }
  float* ep = E + (size_t)blk * SDIM + s0;
  #pragma unroll
  for (int j = 0; j < 4; ++j) ep[j] = h[j];
}

__global__ void k_scan_S(const float* __restrict__ E, const float* __restrict__ A,
                         const float* __restrict__ h0, float* __restrict__ Sb) {
  int blk = blockIdx.x, tid = threadIdx.x;
  int b = blk >> 2;
  int s = ((blk & 3) << 8) + tid;
  float a = A[s], ap = a;
  #pragma unroll
  for (int q = 0; q < 6; ++q) ap *= ap;   // a^64
  float S = h0[s];
  for (int c = 0; c < NC; ++c) {
    size_t idx = ((size_t)b * NC + c) * SDIM + s;
    Sb[idx] = S;
    S = fmaf(ap, S, E[idx]);
  }
}

__global__ void k_scan_h(const short* __restrict__ uB, const float* __restrict__ A,
                         const float* __restrict__ Sb, short* __restrict__ hs) {
  int blk = blockIdx.x, tid = threadIdx.x;
  int b = blk >> 5, c = blk & 31;
  int s0 = tid * 4;
  const short* base = uB + ((size_t)b * SEQ + (size_t)c * LC) * SDIM + s0;
  short* hbase = hs + ((size_t)b * SEQ + (size_t)c * LC) * SDIM + s0;
  float a[4], h[4];
  #pragma unroll
  for (int j = 0; j < 4; ++j) {
    a[j] = A[s0 + j];
    h[j] = Sb[(size_t)blk * SDIM + s0 + j];
  }
  for (int t = 0; t < LC; ++t) {
    bfx4 v = *reinterpret_cast<const bfx4*>(base + (size_t)t * SDIM);
    bfx4 o;
    #pragma unroll
    for (int j = 0; j < 4; ++j) {
      h[j] = fmaf(a[j], h[j], bf2f(v[j]));
      o[j] = (unsigned short)f2bf(h[j]);
    }
    *reinterpret_cast<bfx4*>(hbase + (size_t)t * SDIM) = o;
  }
}

// ================= GEMM1: 128x128, 4 waves, dbuf + counted vmcnt (proven) ====
__device__ __forceinline__ void stage128(const short* __restrict__ g, int ld,
                                         short* l, int tid) {
  int rsub = tid >> 3;
  int slot = (tid & 7) ^ (rsub & 7);
  #pragma unroll
  for (int i = 0; i < 4; ++i) {
    int row = i * 32 + rsub;
    GLOAD16(g + (size_t)row * ld + slot * 8, l + row * 64 + (tid & 7) * 8);
  }
}

__device__ __forceinline__ void mfma_tile(const short* lA, int aoff, const short* lB,
                                          int lane, int wm, int wn, f32x4 acc[4][4]) {
  int lr = lane & 15;
  int h  = lane >> 4;
  #pragma unroll
  for (int kk = 0; kk < 2; ++kk) {
    int kslot = kk * 4 + h;
    short8 af[4], bfr[4];
    #pragma unroll
    for (int mi = 0; mi < 4; ++mi) {
      int row = aoff + wm * 64 + mi * 16 + lr;
      af[mi] = *reinterpret_cast<const short8*>(lA + row * 64 + ((kslot ^ (row & 7)) << 3));
    }
    #pragma unroll
    for (int ni = 0; ni < 4; ++ni) {
      int row = wn * 64 + ni * 16 + lr;
      bfr[ni] = *reinterpret_cast<const short8*>(lB + row * 64 + ((kslot ^ (row & 7)) << 3));
    }
    __builtin_amdgcn_s_setprio(1);
    #pragma unroll
    for (int mi = 0; mi < 4; ++mi)
      #pragma unroll
      for (int ni = 0; ni < 4; ++ni)
        acc[mi][ni] = __builtin_amdgcn_mfma_f32_16x16x32_bf16(af[mi], bfr[ni], acc[mi][ni], 0, 0, 0);
    __builtin_amdgcn_s_setprio(0);
  }
}

__global__ __launch_bounds__(256) void k_gemm_uB(const short* __restrict__ Xp,
                                                 const short* __restrict__ Bt,
                                                 short* __restrict__ uB) {
  __shared__ __attribute__((aligned(16))) short lds[32768];
  short* A0 = lds;         short* B0 = lds + 8192;
  short* A1 = lds + 16384; short* B1 = lds + 24576;
  int tid = threadIdx.x, lane = tid & 63, w = tid >> 6, wm = w >> 1, wn = w & 1;
  long r0 = (long)blockIdx.x * 128;
  int  c0 = blockIdx.y * 128;
  int  b  = (int)(r0 >> 11);
  const short* Abase = Xp + (size_t)(r0 + 16 * (b + 1)) * DIN;
  const short* Bbase = Bt + (size_t)c0 * DIN;
  const f32x4 z4 = {0.f, 0.f, 0.f, 0.f};
  f32x4 acc[4][4];
  #pragma unroll
  for (int mi = 0; mi < 4; ++mi)
    #pragma unroll
    for (int ni = 0; ni < 4; ++ni) acc[mi][ni] = z4;

  stage128(Abase, DIN, A0, tid);      stage128(Bbase, DIN, B0, tid);
  stage128(Abase + 64, DIN, A1, tid); stage128(Bbase + 64, DIN, B1, tid);
  WAITVM(8);
  SBAR();
  for (int kt = 0; kt < 8; ++kt) {
    const short* a  = (kt & 1) ? A1 : A0;
    const short* bb = (kt & 1) ? B1 : B0;
    mfma_tile(a, 0, bb, lane, wm, wn, acc);
    SBAR();
    if (kt + 2 < 8) {
      short* ad = (kt & 1) ? A1 : A0;
      short* bd = (kt & 1) ? B1 : B0;
      stage128(Abase + (kt + 2) * 64, DIN, ad, tid);
      stage128(Bbase + (kt + 2) * 64, DIN, bd, tid);
      WAITVM(8);
    } else {
      WAITVM(0);
    }
    SBAR();
  }
  #pragma unroll
  for (int mi = 0; mi < 4; ++mi)
    #pragma unroll
    for (int ni = 0; ni < 4; ++ni)
      #pragma unroll
      for (int r = 0; r < 4; ++r) {
        long row = r0 + wm * 64 + mi * 16 + (lane >> 4) * 4 + r;
        int  col = c0 + wn * 64 + ni * 16 + (lane & 15);
        uB[(size_t)row * SDIM + col] = f2bf(acc[mi][ni][r]);
      }
}

// ================= GEMM2: 256x128, 8 waves, 3-buf + MFMA/ds_read interleave ===
// LDS (shorts, 81920 = 160 KiB):
//  phase1 tiles: P0=[0,24576) P1=[24576,49152) P2=[49152,73728)  (A 16384 + B 8192)
//  phase2:       Xs0=[0,20480) Xs1=[20480,40960)
//                PM0=[57344,65536) PM1=[65536,73728) PM2=[73728,81920)

struct Frags { short8 a[4][2]; short8 b[4][2]; };

__device__ __forceinline__ void read_frags(Frags& f, const short* la, int aoff,
                                           const short* lb, int lane, int wm, int wn) {
  int lr = lane & 15, h = lane >> 4;
  #pragma unroll
  for (int kk = 0; kk < 2; ++kk) {
    int kslot = kk * 4 + h;
    #pragma unroll
    for (int mi = 0; mi < 4; ++mi) {
      int row = aoff + wm * 64 + mi * 16 + lr;
      f.a[mi][kk] = *reinterpret_cast<const short8*>(la + row * 64 + ((kslot ^ (row & 7)) << 3));
    }
    #pragma unroll
    for (int ni = 0; ni < 4; ++ni) {
      int row = wn * 64 + ni * 16 + lr;
      f.b[ni][kk] = *reinterpret_cast<const short8*>(lb + row * 64 + ((kslot ^ (row & 7)) << 3));
    }
  }
}

__device__ __forceinline__ void mfma_frags(const Frags& f, f32x4 acc[4][4]) {
  #pragma unroll
  for (int kk = 0; kk < 2; ++kk)
    #pragma unroll
    for (int mi = 0; mi < 4; ++mi)
      #pragma unroll
      for (int ni = 0; ni < 4; ++ni)
        acc[mi][ni] = __builtin_amdgcn_mfma_f32_16x16x32_bf16(f.a[mi][kk], f.b[ni][kk], acc[mi][ni], 0, 0, 0);
}

__device__ __forceinline__ void sgb_interleave() {
  #pragma unroll
  for (int i = 0; i < 16; ++i) {
    __builtin_amdgcn_sched_group_barrier(0x008, 2, 0);   // 2 MFMA
    __builtin_amdgcn_sched_group_barrier(0x100, 1, 0);   // 1 DS read
  }
}

__device__ __forceinline__ void stageA256(const short* __restrict__ g, int ld,
                                          short* l, int tid) {
  int rsub = tid >> 3;
  int slot = (tid & 7) ^ (rsub & 7);
  #pragma unroll
  for (int i = 0; i < 4; ++i) {
    int row = i * 64 + rsub;
    GLOAD16(g + (size_t)row * ld + slot * 8, l + row * 64 + (tid & 7) * 8);
  }
}
__device__ __forceinline__ void stageB128(const short* __restrict__ g, int ld,
                                          short* l, int tid) {
  int rsub = tid >> 3;
  int slot = (tid & 7) ^ (rsub & 7);
  #pragma unroll
  for (int i = 0; i < 2; ++i) {
    int row = i * 64 + rsub;
    GLOAD16(g + (size_t)row * ld + slot * 8, l + row * 64 + (tid & 7) * 8);
  }
}
__device__ __forceinline__ void stageX320(const short* __restrict__ g,
                                          short* l, int tid) {
  int rsub = tid >> 3;
  int slot = (tid & 7) ^ (rsub & 7);
  #pragma unroll
  for (int i = 0; i < 5; ++i) {
    int row = i * 64 + rsub;
    GLOAD16(g + (size_t)row * DIN + slot * 8, l + row * 64 + (tid & 7) * 8);
  }
}

__global__ __launch_bounds__(512, 2) void k_gemm_out(const short* __restrict__ hs,
                                                     const short* __restrict__ Xp,
                                                     const short* __restrict__ Ct,
                                                     const short* __restrict__ Mt,
                                                     float* __restrict__ out) {
  __shared__ __attribute__((aligned(16))) short lds[81920];
  short* const P0  = lds;
  short* const P1  = lds + 24576;
  short* const P2  = lds + 49152;
  short* const Xs0 = lds;
  short* const Xs1 = lds + 20480;
  short* const PM0 = lds + 57344;
  short* const PM1 = lds + 65536;
  short* const PM2 = lds + 73728;
  int tid = threadIdx.x, lane = tid & 63, w = tid >> 6;
  int wm = w >> 1, wn = w & 1;                  // 4M x 2N waves, 64x64 each
  int bid = blockIdx.x;
  int sw  = (bid & 7) * 32 + (bid >> 3);        // XCD-bijective over 256
  long r0 = (long)(sw & 63) * 256;
  int  c0 = (sw >> 6) * 128;
  int  b  = (int)(r0 >> 11);
  const short* hsA = hs + (size_t)r0 * SDIM;
  const short* CtB = Ct + (size_t)c0 * SDIM;
  const short* Xa  = Xp + (size_t)(r0 + 16 * (b + 1) - 16) * DIN;
  const short* MtB = Mt + (size_t)c0 * DIN;

  const f32x4 z4 = {0.f, 0.f, 0.f, 0.f};
  f32x4 acc[4][4];
  #pragma unroll
  for (int mi = 0; mi < 4; ++mi)
    #pragma unroll
    for (int ni = 0; ni < 4; ++ni) acc[mi][ni] = z4;

  Frags fr[2];

  // ---- prologue: stage tiles 0,1,2; read frags(0) ----
  stageA256(hsA,        SDIM, P0, tid);  stageB128(CtB,        SDIM, P0 + 16384, tid);
  stageA256(hsA + 64,   SDIM, P1, tid);  stageB128(CtB + 64,   SDIM, P1 + 16384, tid);
  stageA256(hsA + 128,  SDIM, P2, tid);  stageB128(CtB + 128,  SDIM, P2 + 16384, tid);
  WAITVM(6);                 // tiles 0,1 landed; tile 2 in flight
  SBAR();
  read_frags(fr[0], P0, 0, P0 + 16384, lane, wm, wn);

  // ---- phase 1: hs @ Ct^T, 16 steps ----
  #pragma unroll
  for (int s = 0; s < 16; ++s) {
    __builtin_amdgcn_s_setprio(1);
    mfma_frags(fr[s & 1], acc);
    if (s < 15) {
      const short* nb = ((s + 1) % 3 == 0) ? P0 : ((s + 1) % 3 == 1) ? P1 : P2;
      read_frags(fr[(s + 1) & 1], nb, 0, nb + 16384, lane, wm, wn);
    } else {
      read_frags(fr[0], Xs0, 16, PM0, lane, wm, wn);   // phase-2 g=0 frags
    }
    sgb_interleave();
    __builtin_amdgcn_s_setprio(0);
    LGKM0();
    SBAR();
    if (s <= 12) {
      short* sp = (s % 3 == 0) ? P0 : (s % 3 == 1) ? P1 : P2;
      stageA256(hsA + (s + 3) * 64, SDIM, sp, tid);
      stageB128(CtB + (s + 3) * 64, SDIM, sp + 16384, tid);
      WAITVM(6);               // drains tile s+2; tile s+3 in flight
    } else if (s == 13) {
      stageB128(MtB, DIN, PM0, tid);
      stageB128(MtB + (size_t)DOUT * DIN, DIN, PM1, tid);
      WAITVM(4);               // drains tile 15; M0,M1 in flight
    } else if (s == 14) {
      stageB128(MtB + (size_t)2 * DOUT * DIN, DIN, PM2, tid);
      stageX320(Xa, Xs0, tid);
      WAITVM(0);               // phase boundary: drain M0..M2 + X0
    }                           // s == 15: no stage, nothing outstanding
    SBAR();
  }

  // ---- phase 2: AR conv, 8 slices x 10 taps ----
  for (int k0 = 0; k0 < 8; ++k0) {
    int kc = k0 * 64;
    const short* xs = (k0 & 1) ? Xs1 : Xs0;
    short*       xn = (k0 & 1) ? Xs0 : Xs1;
    const short* q0 = (k0 % 3 == 0) ? PM0 : (k0 % 3 == 1) ? PM1 : PM2;
    const short* q1 = (k0 % 3 == 0) ? PM1 : (k0 % 3 == 1) ? PM2 : PM0;
    const short* q2 = (k0 % 3 == 0) ? PM2 : (k0 % 3 == 1) ? PM0 : PM1;
    #pragma unroll
    for (int j = 0; j < KX; ++j) {
      __builtin_amdgcn_s_setprio(1);
      mfma_frags(fr[j & 1], acc);
      bool do_read = (j < 9) || (k0 < 7);
      if (j < 9) {
        const short* mn = ((j + 1) % 3 == 0) ? q0 : ((j + 1) % 3 == 1) ? q1 : q2;
        read_frags(fr[(j + 1) & 1], xs, 15 - j, mn, lane, wm, wn);
      } else if (k0 < 7) {
        read_frags(fr[0], xn, 16, q1, lane, wm, wn);   // next slice tap 0
      }
      if (do_read) sgb_interleave();
      __builtin_amdgcn_s_setprio(0);
      LGKM0();
      SBAR();
      // stage M(g+3)
      if (j + 3 <= 9) {
        short* mw = (j % 3 == 0) ? (short*)q0 : (j % 3 == 1) ? (short*)q1 : (short*)q2;
        stageB128(MtB + (size_t)(j + 3) * DOUT * DIN + kc, DIN, mw, tid);
      } else if (k0 < 7) {
        short* mw = (j % 3 == 0) ? (short*)q0 : (j % 3 == 1) ? (short*)q1 : (short*)q2;
        stageB128(MtB + (size_t)(j - 7) * DOUT * DIN + kc + 64, DIN, mw, tid);
      }
      if (j == 1 && k0 < 7) stageX320(Xa + kc + 64, xn, tid);
      if (j == 1 || j == 2) {
        if (k0 < 7) { WAITVM(7); } else { WAITVM(2); }
      } else if (j >= 7) {
        if (k0 == 7) { WAITVM(0); } else { WAITVM(2); }
      } else {
        WAITVM(2);
      }
      SBAR();
    }
  }

  #pragma unroll
  for (int mi = 0; mi < 4; ++mi)
    #pragma unroll
    for (int ni = 0; ni < 4; ++ni)
      #pragma unroll
      for (int r = 0; r < 4; ++r) {
        long row = r0 + wm * 64 + mi * 16 + (lane >> 4) * 4 + r;
        int  col = c0 + wn * 64 + ni * 16 + (lane & 15);
        out[(size_t)row * DOUT + col] = acc[mi][ni][r];
      }
}

// ================= launch =================
extern "C" void kernel_launch(void* const* d_in, const int* in_sizes, int n_in,
                              void* d_out, int out_size, void* d_ws, size_t ws_size,
                              hipStream_t stream) {
  (void)in_sizes; (void)n_in; (void)out_size; (void)ws_size;
  const float* x  = (const float*)d_in[0];
  const float* h0 = (const float*)d_in[1];
  const float* A  = (const float*)d_in[2];
  const float* B  = (const float*)d_in[3];
  const float* C  = (const float*)d_in[4];
  const float* M  = (const float*)d_in[5];
  float* out = (float*)d_out;
  char* ws = (char*)d_ws;

  short* Xp  = (short*)(ws + OFF_XP);
  short* uB  = (short*)(ws + OFF_UB);
  short* hsb = (short*)(ws + OFF_HS);
  short* Bt  = (short*)(ws + OFF_BT);
  short* Ct  = (short*)(ws + OFF_CT);
  short* Mt  = (short*)(ws + OFF_MT);
  // scan scratch inside d_out (fully overwritten by k_gemm_out afterwards)
  float* E   = out;                    // B_SZ*NC*SDIM f32 = 1 MiB
  float* Sb  = out + B_SZ * NC * SDIM; // 1 MiB

  k_conv_x<<<2048, 256, 0, stream>>>(x, Xp);
  k_zero_pad<<<32, 256, 0, stream>>>(Xp);
  k_transpose_bf16<<<dim3(SDIM / 32, DIN / 32), 256, 0, stream>>>(B, Bt, DIN, SDIM);
  k_transpose_bf16<<<dim3(DOUT / 32, SDIM / 32), 256, 0, stream>>>(C, Ct, SDIM, DOUT);
  k_prep_M<<<(DOUT * DIN + 255) / 256, 256, 0, stream>>>(M, Mt);

  k_gemm_uB<<<dim3(RTOT / 128, SDIM / 128), 256, 0, stream>>>(Xp, Bt, uB);

  k_scan_E<<<B_SZ * NC, 256, 0, stream>>>(uB, A, E);
  k_scan_S<<<B_SZ * 4, 256, 0, stream>>>(E, A, h0, Sb);
  k_scan_h<<<B_SZ * NC, 256, 0, stream>>>(uB, A, Sb, hsb);

  k_gemm_out<<<256, 512, 0, stream>>>(hsb, Xp, Ct, Mt, out);
}